// Round 6
// baseline (142.685 us; speedup 1.0000x reference)
//
#include <hip/hip_runtime.h>
#include <hip/hip_cooperative_groups.h>

namespace cg = cooperative_groups;

#define NPOS 288
#define PSTRIDE 1056   // 32 c * 33 floats (16 mu-acc, 16 var-acc, 1 rsum)
// coop layout: 3 chunks of 96 n per position
#define CNCH 3
#define CCHUNK 96
// pipeline fallback layout: 6 chunks of 48 n
#define NCH 6
#define CHUNK 48

// ---------------------------------------------------------------------------
// Cooperative single-kernel version: 864 blocks x 256 thr, grid.sync between
// EM iterations. Pose staged in LDS ONCE (vs 3x in the pipeline); 3 launch
// drains removed. Partials double-buffered in d_ws; __threadfence before
// grid.sync for cross-XCD visibility (G16).
// PLAIN __launch_bounds__ only (R1/R4: the min-waves arg halves the VGPR
// budget vs expectation and causes 200MB/dispatch scratch spills).
// ---------------------------------------------------------------------------
__global__ __launch_bounds__(256) void caps_coop(
    const float* __restrict__ xg,
    const float* __restrict__ ag,
    const float* __restrict__ wg,
    const float* __restrict__ bu,
    const float* __restrict__ ba,
    float* __restrict__ buf0,
    float* __restrict__ buf1,
    float* __restrict__ outp)
{
    __shared__ __align__(16) float pose_s[CCHUNK * 16];   // 96 n x 16 p = 6KB
    __shared__ float a_s[CCHUNK];
    __shared__ __align__(16) float scratch[4 * 32 * 33];  // 16.9KB
    __shared__ float rsum_part[4 * 32];
    __shared__ float mu_tab[512];
    __shared__ float i2s_tab[512];
    __shared__ float Kc_tab[32];

    cg::grid_group grid = cg::this_grid();

    const int tid = threadIdx.x;
    const int blk = blockIdx.x;
    const int pos = blk / CNCH;
    const int ch  = blk - pos * CNCH;    // kh row of the 3x3 window
    const int bb  = pos / 36;
    const int rem = pos % 36;
    const int yy  = rem / 6;
    const int xx  = rem % 6;

    // ---- stage this chunk's 96x16 pose slice ONCE (persists across iters) ----
    // element e: cell = e>>9 (kw 0..2, 512 floats per window cell), off = e&511
    #pragma unroll
    for (int j = 0; j < 6; ++j) {
        const int e    = j * 256 + tid;
        const int cell = e >> 9;
        const int off  = e & 511;
        pose_s[e] =
            xg[(size_t)((((bb * 14) + (2 * yy + ch)) * 14 + (2 * xx + cell)) * 32) * 16 + off];
    }
    if (tid < CCHUNK) {
        const int cell = tid >> 5, bi = tid & 31;
        a_s[tid] = ag[(size_t)(((bb * 14) + (2 * yy + ch)) * 14 + (2 * xx + cell)) * 32 + bi];
    }
    __syncthreads();

    const int c    = tid & 31;   // capsule-out index
    const int s    = tid >> 5;   // n-slice 0..7 (12 n each)
    const int lane = tid & 63;
    const int wv   = tid >> 6;   // wave 0..3
    const int fc2  = tid >> 3;   // 0..31 (finalize c index)
    const int fh   = tid & 7;    // 0..7  (p half-index)
    const float4* wp = (const float4*)wg;

    for (int it = 0; it < 3; ++it) {
        const float* pin  = (it == 2) ? buf1 : buf0;  // it1 reads buf0, it2 reads buf1
        float*       pout = (it == 1) ? buf1 : buf0;  // it0->buf0, it1->buf1, it2->buf0

        float mu_c[16], i2s_c[16], Kc = 0.f;
        if (it > 0) {
            // ---- redundant finalize of previous iteration from global partials ----
            const float* q0 = pin + (size_t)pos * (CNCH * PSTRIDE) + fc2 * 33;
            float ms0 = 0.f, ms1 = 0.f, vs0 = 0.f, vs1 = 0.f, rsc = 0.f;
            #pragma unroll
            for (int cc = 0; cc < CNCH; ++cc) {
                const float* q = q0 + cc * PSTRIDE;
                ms0 += q[fh];
                ms1 += q[fh + 8];
                vs0 += q[16 + fh];
                vs1 += q[16 + fh + 8];
                rsc += q[32];
            }
            const float inv  = 1.f / (rsc + 1e-6f);
            const float S    = rsc * inv;
            const float mu0  = ms0 * inv;
            const float mu1  = ms1 * inv;
            const float sig0 = vs0 * inv - mu0 * mu0 * (2.f - S) + 1e-6f;
            const float sig1 = vs1 * inv - mu1 * mu1 * (2.f - S) + 1e-6f;
            float lgs = __logf(sig0) + __logf(sig1);
            #pragma unroll
            for (int msk = 4; msk >= 1; msk >>= 1) lgs += __shfl_xor(lgs, msk);
            const float cost = rsc * (16.f * bu[fc2] + 0.5f * lgs);
            const float ao   = 1.f / (1.f + __expf(-0.001f * (ba[fc2] - cost)));
            mu_tab[fc2 * 16 + fh]      = mu0;
            mu_tab[fc2 * 16 + fh + 8]  = mu1;
            i2s_tab[fc2 * 16 + fh]     = 0.5f / sig0;
            i2s_tab[fc2 * 16 + fh + 8] = 0.5f / sig1;
            if (fh == 0) Kc_tab[fc2] = 0.5f * lgs - __logf(ao);
            __syncthreads();
            #pragma unroll
            for (int p = 0; p < 16; ++p) {
                mu_c[p]  = mu_tab[c * 16 + p];
                i2s_c[p] = i2s_tab[c * 16 + p];
            }
            Kc = Kc_tab[c];
        }

        float macc[16], vacc[16], rs = 0.f;
        #pragma unroll
        for (int p = 0; p < 16; ++p) { macc[p] = 0.f; vacc[p] = 0.f; }

        // ---- fused E+M pass over this thread's 12 n values ----
        for (int k = 0; k < 12; ++k) {
            const int nl = s * 12 + k;           // 0..95 within chunk
            const int n  = ch * CCHUNK + nl;     // global n
            const float4* pp = (const float4*)&pose_s[nl << 4];
            float pf[16];
            float4 q;
            q = pp[0]; pf[0]=q.x;  pf[1]=q.y;  pf[2]=q.z;  pf[3]=q.w;
            q = pp[1]; pf[4]=q.x;  pf[5]=q.y;  pf[6]=q.z;  pf[7]=q.w;
            q = pp[2]; pf[8]=q.x;  pf[9]=q.y;  pf[10]=q.z; pf[11]=q.w;
            q = pp[3]; pf[12]=q.x; pf[13]=q.y; pf[14]=q.z; pf[15]=q.w;
            const int wbase = (n * 32 + c) * 4;
            float v[16];
            #pragma unroll
            for (int p = 0; p < 16; ++p) v[p] = 0.f;
            #pragma unroll
            for (int j = 0; j < 4; ++j) {
                const float4 w = wp[wbase + j];
                #pragma unroll
                for (int i = 0; i < 4; ++i) {
                    const float pj = pf[i * 4 + j];
                    v[i*4+0] = fmaf(pj, w.x, v[i*4+0]);
                    v[i*4+1] = fmaf(pj, w.y, v[i*4+1]);
                    v[i*4+2] = fmaf(pj, w.z, v[i*4+2]);
                    v[i*4+3] = fmaf(pj, w.w, v[i*4+3]);
                }
            }
            float r;
            if (it == 0) {
                r = a_s[nl] * 0.03125f;  // (1/C) * a_in
            } else {
                float t0 = 0.f, t1 = 0.f, t2 = 0.f, t3 = 0.f;
                #pragma unroll
                for (int p = 0; p < 16; p += 4) {
                    float d0 = v[p]   - mu_c[p];   t0 = fmaf(d0*d0, i2s_c[p],   t0);
                    float d1 = v[p+1] - mu_c[p+1]; t1 = fmaf(d1*d1, i2s_c[p+1], t1);
                    float d2 = v[p+2] - mu_c[p+2]; t2 = fmaf(d2*d2, i2s_c[p+2], t2);
                    float d3 = v[p+3] - mu_c[p+3]; t3 = fmaf(d3*d3, i2s_c[p+3], t3);
                }
                float lnap = -((t0 + t1) + (t2 + t3)) - Kc;
                float m = lnap;
                #pragma unroll
                for (int msk = 16; msk >= 1; msk >>= 1) m = fmaxf(m, __shfl_xor(m, msk));
                float e = __expf(lnap - m);
                float sum = e;
                #pragma unroll
                for (int msk = 16; msk >= 1; msk >>= 1) sum += __shfl_xor(sum, msk);
                r = e / sum;
            }
            rs += r;
            #pragma unroll
            for (int p = 0; p < 16; ++p) {
                float rv = r * v[p];
                macc[p] += rv;
                vacc[p] = fmaf(rv, v[p], vacc[p]);
            }
        }

        // ---- reduce 8 n-slices: shfl pair, then LDS across 4 waves ----
        #pragma unroll
        for (int p = 0; p < 16; ++p) {
            macc[p] += __shfl_xor(macc[p], 32);
            vacc[p] += __shfl_xor(vacc[p], 32);
        }
        rs += __shfl_xor(rs, 32);
        if (lane < 32) {  // c = lane
            const int base = (wv * 32 + lane) * 33;
            #pragma unroll
            for (int p = 0; p < 16; ++p) {
                scratch[base + p]      = macc[p];
                scratch[base + 16 + p] = vacc[p];
            }
            rsum_part[wv * 32 + lane] = rs;
        }
        __syncthreads();

        // ---- block-level sum -> write chunk partials ----
        float ms0 = 0.f, ms1 = 0.f, vs0 = 0.f, vs1 = 0.f, rsc = 0.f;
        #pragma unroll
        for (int w = 0; w < 4; ++w) {
            const int base = (w * 32 + fc2) * 33;
            ms0 += scratch[base + fh];
            ms1 += scratch[base + fh + 8];
            vs0 += scratch[base + 16 + fh];
            vs1 += scratch[base + 16 + fh + 8];
            rsc += rsum_part[w * 32 + fc2];
        }
        float* po = pout + (size_t)(pos * CNCH + ch) * PSTRIDE + fc2 * 33;
        po[fh]          = ms0;
        po[fh + 8]      = ms1;
        po[16 + fh]     = vs0;
        po[16 + fh + 8] = vs1;
        if (fh == 0) po[32] = rsc;

        __threadfence();   // device-scope release of partials (cross-XCD, G16)
        grid.sync();
    }

    // ---- finalize phase: ch==0 blocks write outputs for their pos ----
    if (ch == 0) {
        const float* q0p = buf0 + (size_t)pos * (CNCH * PSTRIDE);
        #pragma unroll
        for (int half = 0; half < 2; ++half) {
            const int fc = (tid >> 4) + half * 16;
            const int fp = tid & 15;
            const float* q0 = q0p + fc * 33;
            float ms = 0.f, vs = 0.f, rsc = 0.f;
            #pragma unroll
            for (int cc = 0; cc < CNCH; ++cc) {
                const float* q = q0 + cc * PSTRIDE;
                ms  += q[fp];
                vs  += q[16 + fp];
                rsc += q[32];
            }
            const float inv = 1.f / (rsc + 1e-6f);
            const float S   = rsc * inv;
            const float mu  = ms * inv;
            const float sig = vs * inv - mu * mu * (2.f - S) + 1e-6f;
            float lgs = __logf(sig);
            #pragma unroll
            for (int msk = 8; msk >= 1; msk >>= 1) lgs += __shfl_xor(lgs, msk);
            const float cost = rsc * (16.f * bu[fc] + 0.5f * lgs);
            const float ao   = 1.f / (1.f + __expf(-0.001f * (ba[fc] - cost)));
            outp[(size_t)pos * 512 + fc * 16 + fp] = mu;
            if (fp == 0) outp[147456 + (size_t)pos * 32 + fc] = ao;
        }
    }
}

// ---------------------------------------------------------------------------
// Fallback pipeline (verified R5): 3 accumulate kernels + finalize.
// ---------------------------------------------------------------------------
template<int IT>
__global__ __launch_bounds__(256) void caps_acc(
    const float* __restrict__ xg,
    const float* __restrict__ ag,
    const float* __restrict__ wg,
    const float* __restrict__ bu,
    const float* __restrict__ ba,
    const float* __restrict__ pin,
    float* __restrict__ pout)
{
    __shared__ __align__(16) float pose_s[CHUNK * 16];
    __shared__ float a_s[CHUNK];
    __shared__ __align__(16) float scratch[4 * 32 * 33];
    __shared__ float rsum_part[4 * 32];
    __shared__ float mu_tab[512];
    __shared__ float i2s_tab[512];
    __shared__ float Kc_tab[32];

    const int tid = threadIdx.x;
    const int blk = blockIdx.x;
    const int pos = blk / NCH;
    const int ch  = blk - pos * NCH;
    const int bb  = pos / 36;
    const int rem = pos % 36;
    const int yy  = rem / 6;
    const int xx  = rem % 6;

    #pragma unroll
    for (int j = 0; j < 3; ++j) {
        const int e    = ch * 768 + j * 256 + tid;
        const int cell = e >> 9;
        const int off  = e & 511;
        const int kh = cell / 3, kw = cell % 3;
        pose_s[j * 256 + tid] =
            xg[(size_t)((((bb * 14) + (2 * yy + kh)) * 14 + (2 * xx + kw)) * 32) * 16 + off];
    }
    if (IT == 0) {
        if (tid < CHUNK) {
            const int e    = ch * CHUNK + tid;
            const int cell = e >> 5;
            const int bi   = e & 31;
            const int kh = cell / 3, kw = cell % 3;
            a_s[tid] = ag[(size_t)(((bb * 14) + (2 * yy + kh)) * 14 + (2 * xx + kw)) * 32 + bi];
        }
    }

    const int fc2 = tid >> 3;
    const int fh  = tid & 7;
    if (IT > 0) {
        const float* q0 = pin + (size_t)pos * (NCH * PSTRIDE) + fc2 * 33;
        float ms0 = 0.f, ms1 = 0.f, vs0 = 0.f, vs1 = 0.f, rsc = 0.f;
        #pragma unroll
        for (int cc = 0; cc < NCH; ++cc) {
            const float* q = q0 + cc * PSTRIDE;
            ms0 += q[fh];
            ms1 += q[fh + 8];
            vs0 += q[16 + fh];
            vs1 += q[16 + fh + 8];
            rsc += q[32];
        }
        const float inv  = 1.f / (rsc + 1e-6f);
        const float S    = rsc * inv;
        const float mu0  = ms0 * inv;
        const float mu1  = ms1 * inv;
        const float sig0 = vs0 * inv - mu0 * mu0 * (2.f - S) + 1e-6f;
        const float sig1 = vs1 * inv - mu1 * mu1 * (2.f - S) + 1e-6f;
        float lgs = __logf(sig0) + __logf(sig1);
        #pragma unroll
        for (int msk = 4; msk >= 1; msk >>= 1) lgs += __shfl_xor(lgs, msk);
        const float cost = rsc * (16.f * bu[fc2] + 0.5f * lgs);
        const float ao   = 1.f / (1.f + __expf(-0.001f * (ba[fc2] - cost)));
        mu_tab[fc2 * 16 + fh]      = mu0;
        mu_tab[fc2 * 16 + fh + 8]  = mu1;
        i2s_tab[fc2 * 16 + fh]     = 0.5f / sig0;
        i2s_tab[fc2 * 16 + fh + 8] = 0.5f / sig1;
        if (fh == 0) Kc_tab[fc2] = 0.5f * lgs - __logf(ao);
    }
    __syncthreads();

    const int c    = tid & 31;
    const int s    = tid >> 5;
    const int lane = tid & 63;
    const int wv   = tid >> 6;
    const float4* wp = (const float4*)wg;

    float mu_c[16], i2s_c[16], Kc = 0.f;
    if (IT > 0) {
        #pragma unroll
        for (int p = 0; p < 16; ++p) {
            mu_c[p]  = mu_tab[c * 16 + p];
            i2s_c[p] = i2s_tab[c * 16 + p];
        }
        Kc = Kc_tab[c];
    }
    float macc[16], vacc[16], rs = 0.f;
    #pragma unroll
    for (int p = 0; p < 16; ++p) { macc[p] = 0.f; vacc[p] = 0.f; }

    for (int k = 0; k < 6; ++k) {
        const int nl = s * 6 + k;
        const int n  = ch * CHUNK + nl;
        const float4* pp = (const float4*)&pose_s[nl << 4];
        float pf[16];
        float4 q;
        q = pp[0]; pf[0]=q.x;  pf[1]=q.y;  pf[2]=q.z;  pf[3]=q.w;
        q = pp[1]; pf[4]=q.x;  pf[5]=q.y;  pf[6]=q.z;  pf[7]=q.w;
        q = pp[2]; pf[8]=q.x;  pf[9]=q.y;  pf[10]=q.z; pf[11]=q.w;
        q = pp[3]; pf[12]=q.x; pf[13]=q.y; pf[14]=q.z; pf[15]=q.w;
        const int wbase = (n * 32 + c) * 4;
        float v[16];
        #pragma unroll
        for (int p = 0; p < 16; ++p) v[p] = 0.f;
        #pragma unroll
        for (int j = 0; j < 4; ++j) {
            const float4 w = wp[wbase + j];
            #pragma unroll
            for (int i = 0; i < 4; ++i) {
                const float pj = pf[i * 4 + j];
                v[i*4+0] = fmaf(pj, w.x, v[i*4+0]);
                v[i*4+1] = fmaf(pj, w.y, v[i*4+1]);
                v[i*4+2] = fmaf(pj, w.z, v[i*4+2]);
                v[i*4+3] = fmaf(pj, w.w, v[i*4+3]);
            }
        }
        float r;
        if (IT == 0) {
            r = a_s[nl] * 0.03125f;
        } else {
            float t0 = 0.f, t1 = 0.f, t2 = 0.f, t3 = 0.f;
            #pragma unroll
            for (int p = 0; p < 16; p += 4) {
                float d0 = v[p]   - mu_c[p];   t0 = fmaf(d0*d0, i2s_c[p],   t0);
                float d1 = v[p+1] - mu_c[p+1]; t1 = fmaf(d1*d1, i2s_c[p+1], t1);
                float d2 = v[p+2] - mu_c[p+2]; t2 = fmaf(d2*d2, i2s_c[p+2], t2);
                float d3 = v[p+3] - mu_c[p+3]; t3 = fmaf(d3*d3, i2s_c[p+3], t3);
            }
            float lnap = -((t0 + t1) + (t2 + t3)) - Kc;
            float m = lnap;
            #pragma unroll
            for (int msk = 16; msk >= 1; msk >>= 1) m = fmaxf(m, __shfl_xor(m, msk));
            float e = __expf(lnap - m);
            float sum = e;
            #pragma unroll
            for (int msk = 16; msk >= 1; msk >>= 1) sum += __shfl_xor(sum, msk);
            r = e / sum;
        }
        rs += r;
        #pragma unroll
        for (int p = 0; p < 16; ++p) {
            float rv = r * v[p];
            macc[p] += rv;
            vacc[p] = fmaf(rv, v[p], vacc[p]);
        }
    }

    #pragma unroll
    for (int p = 0; p < 16; ++p) {
        macc[p] += __shfl_xor(macc[p], 32);
        vacc[p] += __shfl_xor(vacc[p], 32);
    }
    rs += __shfl_xor(rs, 32);
    if (lane < 32) {
        const int base = (wv * 32 + lane) * 33;
        #pragma unroll
        for (int p = 0; p < 16; ++p) {
            scratch[base + p]      = macc[p];
            scratch[base + 16 + p] = vacc[p];
        }
        rsum_part[wv * 32 + lane] = rs;
    }
    __syncthreads();

    float ms0 = 0.f, ms1 = 0.f, vs0 = 0.f, vs1 = 0.f, rsc = 0.f;
    #pragma unroll
    for (int w = 0; w < 4; ++w) {
        const int base = (w * 32 + fc2) * 33;
        ms0 += scratch[base + fh];
        ms1 += scratch[base + fh + 8];
        vs0 += scratch[base + 16 + fh];
        vs1 += scratch[base + 16 + fh + 8];
        rsc += rsum_part[w * 32 + fc2];
    }
    float* po = pout + (size_t)(pos * NCH + ch) * PSTRIDE + fc2 * 33;
    po[fh]          = ms0;
    po[fh + 8]      = ms1;
    po[16 + fh]     = vs0;
    po[16 + fh + 8] = vs1;
    if (fh == 0) po[32] = rsc;
}

__global__ __launch_bounds__(512) void caps_fin(
    const float* __restrict__ pin,
    const float* __restrict__ bu,
    const float* __restrict__ ba,
    float* __restrict__ outp)
{
    const int tid = threadIdx.x;
    const int pos = blockIdx.x;
    const int fc = tid >> 4, fp = tid & 15;
    const float* q0 = pin + (size_t)pos * (NCH * PSTRIDE) + fc * 33;
    float ms = 0.f, vs = 0.f, rsc = 0.f;
    #pragma unroll
    for (int cc = 0; cc < NCH; ++cc) {
        const float* q = q0 + cc * PSTRIDE;
        ms  += q[fp];
        vs  += q[16 + fp];
        rsc += q[32];
    }
    const float inv = 1.f / (rsc + 1e-6f);
    const float S   = rsc * inv;
    const float mu  = ms * inv;
    const float sig = vs * inv - mu * mu * (2.f - S) + 1e-6f;
    float lgs = __logf(sig);
    #pragma unroll
    for (int msk = 8; msk >= 1; msk >>= 1) lgs += __shfl_xor(lgs, msk);
    const float cost = rsc * (16.f * bu[fc] + 0.5f * lgs);
    const float ao   = 1.f / (1.f + __expf(-0.001f * (ba[fc] - cost)));
    outp[(size_t)pos * 512 + tid] = mu;
    if (fp == 0) outp[147456 + (size_t)pos * 32 + fc] = ao;
}

// ---------------------------------------------------------------------------
// Fallback: single fused kernel (used only if workspace too small).
// ---------------------------------------------------------------------------
__global__ __launch_bounds__(512) void convcaps_kernel(
    const float* __restrict__ xg,
    const float* __restrict__ ag,
    const float* __restrict__ wg,
    const float* __restrict__ bu,
    const float* __restrict__ ba,
    float* __restrict__ outp)
{
    __shared__ __align__(16) float pose_s[4608];
    __shared__ float a_s[288];
    __shared__ __align__(16) float scratch[8448];
    __shared__ float rsum_part[256];
    __shared__ float mu_tab[512];
    __shared__ float i2s_tab[512];
    __shared__ float Kc_tab[32];

    const int tid = threadIdx.x;
    const int pos = blockIdx.x;
    const int bb  = pos / 36;
    const int rem = pos % 36;
    const int yy  = rem / 6;
    const int xx  = rem % 6;

    #pragma unroll
    for (int wi = 0; wi < 9; ++wi) {
        const int kh = wi / 3, kw = wi % 3;
        const float* src =
            xg + (size_t)((((bb * 14) + (2 * yy + kh)) * 14 + (2 * xx + kw)) * 32) * 16;
        pose_s[wi * 512 + tid] = src[tid];
    }
    if (tid < 288) {
        const int wi = tid >> 5, bi = tid & 31;
        const int kh = wi / 3, kw = wi % 3;
        a_s[tid] = ag[(size_t)(((bb * 14) + (2 * yy + kh)) * 14 + (2 * xx + kw)) * 32 + bi];
    }
    __syncthreads();

    const int c    = tid & 31;
    const int s    = tid >> 5;
    const int lane = tid & 63;
    const int wv   = tid >> 6;
    const float4* wp = (const float4*)wg;

    for (int it = 0; it < 3; ++it) {
        float mu_c[16], i2s_c[16], Kc = 0.f;
        if (it > 0) {
            #pragma unroll
            for (int p = 0; p < 16; ++p) {
                mu_c[p]  = mu_tab[c * 16 + p];
                i2s_c[p] = i2s_tab[c * 16 + p];
            }
            Kc = Kc_tab[c];
        }
        float macc[16], vacc[16], rs = 0.f;
        #pragma unroll
        for (int p = 0; p < 16; ++p) { macc[p] = 0.f; vacc[p] = 0.f; }

        for (int k = 0; k < 18; ++k) {
            const int n = s * 18 + k;
            const float4* pp = (const float4*)&pose_s[n << 4];
            float pf[16];
            float4 q;
            q = pp[0]; pf[0]=q.x; pf[1]=q.y; pf[2]=q.z;  pf[3]=q.w;
            q = pp[1]; pf[4]=q.x; pf[5]=q.y; pf[6]=q.z;  pf[7]=q.w;
            q = pp[2]; pf[8]=q.x; pf[9]=q.y; pf[10]=q.z; pf[11]=q.w;
            q = pp[3]; pf[12]=q.x; pf[13]=q.y; pf[14]=q.z; pf[15]=q.w;
            const int wbase = (n * 32 + c) * 4;
            float v[16];
            #pragma unroll
            for (int p = 0; p < 16; ++p) v[p] = 0.f;
            #pragma unroll
            for (int j = 0; j < 4; ++j) {
                const float4 w = wp[wbase + j];
                #pragma unroll
                for (int i = 0; i < 4; ++i) {
                    const float pj = pf[i * 4 + j];
                    v[i*4+0] = fmaf(pj, w.x, v[i*4+0]);
                    v[i*4+1] = fmaf(pj, w.y, v[i*4+1]);
                    v[i*4+2] = fmaf(pj, w.z, v[i*4+2]);
                    v[i*4+3] = fmaf(pj, w.w, v[i*4+3]);
                }
            }
            float r;
            if (it == 0) {
                r = a_s[n] * 0.03125f;
            } else {
                float t = 0.f;
                #pragma unroll
                for (int p = 0; p < 16; ++p) {
                    float d = v[p] - mu_c[p];
                    t = fmaf(d * d, i2s_c[p], t);
                }
                float lnap = -t - Kc;
                float m = lnap;
                #pragma unroll
                for (int msk = 16; msk >= 1; msk >>= 1) m = fmaxf(m, __shfl_xor(m, msk));
                float e = __expf(lnap - m);
                float sum = e;
                #pragma unroll
                for (int msk = 16; msk >= 1; msk >>= 1) sum += __shfl_xor(sum, msk);
                r = e / sum;
            }
            rs += r;
            #pragma unroll
            for (int p = 0; p < 16; ++p) {
                float rv = r * v[p];
                macc[p] += rv;
                vacc[p] = fmaf(rv, v[p], vacc[p]);
            }
        }

        #pragma unroll
        for (int p = 0; p < 16; ++p) {
            macc[p] += __shfl_xor(macc[p], 32);
            vacc[p] += __shfl_xor(vacc[p], 32);
        }
        rs += __shfl_xor(rs, 32);
        if (lane < 32) {
            const int base = (wv * 32 + lane) * 33;
            #pragma unroll
            for (int p = 0; p < 16; ++p) {
                scratch[base + p]      = macc[p];
                scratch[base + 16 + p] = vacc[p];
            }
            rsum_part[wv * 32 + lane] = rs;
        }
        __syncthreads();

        const int fc = tid >> 4, fp = tid & 15;
        float ms = 0.f, vs = 0.f, rsc = 0.f;
        #pragma unroll
        for (int w = 0; w < 8; ++w) {
            ms  += scratch[(w * 32 + fc) * 33 + fp];
            vs  += scratch[(w * 32 + fc) * 33 + 16 + fp];
            rsc += rsum_part[w * 32 + fc];
        }
        const float inv = 1.f / (rsc + 1e-6f);
        const float S   = rsc * inv;
        const float mu  = ms * inv;
        const float sig = vs * inv - mu * mu * (2.f - S) + 1e-6f;
        float lgs = __logf(sig);
        #pragma unroll
        for (int msk = 8; msk >= 1; msk >>= 1) lgs += __shfl_xor(lgs, msk);
        const float cost = rsc * (16.f * bu[fc] + 0.5f * lgs);
        const float ao   = 1.f / (1.f + __expf(-0.001f * (ba[fc] - cost)));

        mu_tab[fc * 16 + fp]  = mu;
        i2s_tab[fc * 16 + fp] = 0.5f / sig;
        if (fp == 0) Kc_tab[fc] = 0.5f * lgs - __logf(ao);

        if (it == 2) {
            outp[(size_t)pos * 512 + tid] = mu;
            if (fp == 0) outp[147456 + (size_t)pos * 32 + fc] = ao;
        }
        __syncthreads();
    }
}

extern "C" void kernel_launch(void* const* d_in, const int* in_sizes, int n_in,
                              void* d_out, int out_size, void* d_ws, size_t ws_size,
                              hipStream_t stream) {
    (void)in_sizes; (void)n_in; (void)out_size;
    const float* x  = (const float*)d_in[0];
    const float* a  = (const float*)d_in[1];
    const float* w  = (const float*)d_in[2];
    const float* bu = (const float*)d_in[3];
    const float* ba = (const float*)d_in[4];
    float* out = (float*)d_out;

    const size_t buf_elems = (size_t)NPOS * NCH * PSTRIDE;  // sized for pipeline layout (superset)
    if (ws_size < 2 * buf_elems * sizeof(float)) {
        convcaps_kernel<<<dim3(288), dim3(512), 0, stream>>>(x, a, w, bu, ba, out);
        return;
    }
    float* buf0 = (float*)d_ws;
    float* buf1 = buf0 + buf_elems;

    // one-time cooperative feasibility check (pure host queries, capture-safe)
    static int coop_ok = -1;
    if (coop_ok < 0) {
        int dev = 0;
        (void)hipGetDevice(&dev);
        int coopAttr = 0, nCU = 0, nb = 0;
        (void)hipDeviceGetAttribute(&coopAttr, hipDeviceAttributeCooperativeLaunch, dev);
        (void)hipDeviceGetAttribute(&nCU, hipDeviceAttributeMultiprocessorCount, dev);
        hipError_t oe = hipOccupancyMaxActiveBlocksPerMultiprocessor(&nb, caps_coop, 256, 0);
        coop_ok = (coopAttr != 0 && oe == hipSuccess && nCU > 0 &&
                   (long)nb * (long)nCU >= (long)(NPOS * CNCH)) ? 1 : 0;
    }

    if (coop_ok == 1) {
        void* args[8];
        args[0] = (void*)&x;  args[1] = (void*)&a;  args[2] = (void*)&w;
        args[3] = (void*)&bu; args[4] = (void*)&ba;
        args[5] = (void*)&buf0; args[6] = (void*)&buf1; args[7] = (void*)&out;
        hipError_t e = hipLaunchCooperativeKernel((const void*)caps_coop,
                                                  dim3(NPOS * CNCH), dim3(256),
                                                  args, 0, stream);
        if (e == hipSuccess) return;
        coop_ok = 0;  // fall through to pipeline
    }

    caps_acc<0><<<dim3(NPOS * NCH), dim3(256), 0, stream>>>(x, a, w, bu, ba, nullptr, buf0);
    caps_acc<1><<<dim3(NPOS * NCH), dim3(256), 0, stream>>>(x, a, w, bu, ba, buf0, buf1);
    caps_acc<2><<<dim3(NPOS * NCH), dim3(256), 0, stream>>>(x, a, w, bu, ba, buf1, buf0);
    caps_fin<<<dim3(NPOS), dim3(512), 0, stream>>>(buf0, bu, ba, out);
}

// Round 7
// 127.217 us; speedup vs baseline: 1.1216x; 1.1216x over previous
//
#include <hip/hip_runtime.h>
#include <hip/hip_cooperative_groups.h>

namespace cg = cooperative_groups;

#define NPOS 288
#define PSTRIDE 1056   // 32 c * 33 floats (16 mu-acc, 16 var-acc, 1 rsum)
// coop layout: 3 chunks of 96 n per position
#define CNCH 3
#define CCHUNK 96
// pipeline fallback layout: 6 chunks of 48 n
#define NCH 6
#define CHUNK 48

// ---- DPP 32-lane (half-wave) reductions: 4 VALU-pipe row_ror steps + one
// cross-row shfl_xor(16). Replaces the 5-step ds_swizzle trees (10 DS ops ->
// 2 DS ops per softmax, chain ~250cyc -> ~60cyc). Groups are lanes [0,32) and
// [32,64) == c=tid&31, matching rows {0,1} and {2,3}.
template<int CTRL>
__device__ __forceinline__ float dpp_mov(float x) {
    return __int_as_float(__builtin_amdgcn_update_dpp(
        0, __float_as_int(x), CTRL, 0xF, 0xF, true));
}
__device__ __forceinline__ float red32_max(float x) {
    x = fmaxf(x, dpp_mov<0x121>(x));  // row_ror:1
    x = fmaxf(x, dpp_mov<0x122>(x));  // row_ror:2
    x = fmaxf(x, dpp_mov<0x124>(x));  // row_ror:4
    x = fmaxf(x, dpp_mov<0x128>(x));  // row_ror:8
    return fmaxf(x, __shfl_xor(x, 16));
}
__device__ __forceinline__ float red32_sum(float x) {
    x += dpp_mov<0x121>(x);
    x += dpp_mov<0x122>(x);
    x += dpp_mov<0x124>(x);
    x += dpp_mov<0x128>(x);
    return x + __shfl_xor(x, 16);
}

// v row: dot of pose row (pa) against W columns
#define DOT4(pa, c0, c1, c2, c3) fmaf(pa.x, c0, fmaf(pa.y, c1, fmaf(pa.z, c2, pa.w * c3)))
#define VROWS() \
    v0.x = DOT4(pa0, wa0.x, wa1.x, wa2.x, wa3.x); \
    v0.y = DOT4(pa0, wa0.y, wa1.y, wa2.y, wa3.y); \
    v0.z = DOT4(pa0, wa0.z, wa1.z, wa2.z, wa3.z); \
    v0.w = DOT4(pa0, wa0.w, wa1.w, wa2.w, wa3.w); \
    v1.x = DOT4(pa1, wa0.x, wa1.x, wa2.x, wa3.x); \
    v1.y = DOT4(pa1, wa0.y, wa1.y, wa2.y, wa3.y); \
    v1.z = DOT4(pa1, wa0.z, wa1.z, wa2.z, wa3.z); \
    v1.w = DOT4(pa1, wa0.w, wa1.w, wa2.w, wa3.w); \
    v2.x = DOT4(pa2, wa0.x, wa1.x, wa2.x, wa3.x); \
    v2.y = DOT4(pa2, wa0.y, wa1.y, wa2.y, wa3.y); \
    v2.z = DOT4(pa2, wa0.z, wa1.z, wa2.z, wa3.z); \
    v2.w = DOT4(pa2, wa0.w, wa1.w, wa2.w, wa3.w); \
    v3.x = DOT4(pa3, wa0.x, wa1.x, wa2.x, wa3.x); \
    v3.y = DOT4(pa3, wa0.y, wa1.y, wa2.y, wa3.y); \
    v3.z = DOT4(pa3, wa0.z, wa1.z, wa2.z, wa3.z); \
    v3.w = DOT4(pa3, wa0.w, wa1.w, wa2.w, wa3.w);
#define TACC(ti, vi, mui, isi) \
    { float d_; \
      d_ = vi.x - mui.x; ti = fmaf(d_*d_, isi.x, ti); \
      d_ = vi.y - mui.y; ti = fmaf(d_*d_, isi.y, ti); \
      d_ = vi.z - mui.z; ti = fmaf(d_*d_, isi.z, ti); \
      d_ = vi.w - mui.w; ti = fmaf(d_*d_, isi.w, ti); }
#define MACC(mai, vai, vi) \
    { float rv_; \
      rv_ = r * vi.x; mai.x += rv_; vai.x = fmaf(rv_, vi.x, vai.x); \
      rv_ = r * vi.y; mai.y += rv_; vai.y = fmaf(rv_, vi.y, vai.y); \
      rv_ = r * vi.z; mai.z += rv_; vai.z = fmaf(rv_, vi.z, vai.z); \
      rv_ = r * vi.w; mai.w += rv_; vai.w = fmaf(rv_, vi.w, vai.w); }
#define XRED(vi) \
    vi.x += __shfl_xor(vi.x, 32); vi.y += __shfl_xor(vi.y, 32); \
    vi.z += __shfl_xor(vi.z, 32); vi.w += __shfl_xor(vi.w, 32);

// ---------------------------------------------------------------------------
// Cooperative single-kernel version: 864 blocks x 256 thr, grid.sync between
// EM iterations. W loads double-buffered across the k-loop (hide L2 latency);
// softmax c-reduction via DPP (VALU pipe) instead of ds_swizzle trees.
// PLAIN __launch_bounds__ only (R1/R4: min-waves arg => spill catastrophe).
// ---------------------------------------------------------------------------
__global__ __launch_bounds__(256) void caps_coop(
    const float* __restrict__ xg,
    const float* __restrict__ ag,
    const float* __restrict__ wg,
    const float* __restrict__ bu,
    const float* __restrict__ ba,
    float* __restrict__ buf0,
    float* __restrict__ buf1,
    float* __restrict__ outp)
{
    __shared__ __align__(16) float pose_s[CCHUNK * 16];
    __shared__ float a_s[CCHUNK];
    __shared__ __align__(16) float scratch[4 * 32 * 33];
    __shared__ float rsum_part[4 * 32];
    __shared__ float mu_tab[512];
    __shared__ float i2s_tab[512];
    __shared__ float Kc_tab[32];

    cg::grid_group grid = cg::this_grid();

    const int tid = threadIdx.x;
    const int blk = blockIdx.x;
    const int pos = blk / CNCH;
    const int ch  = blk - pos * CNCH;
    const int bb  = pos / 36;
    const int rem = pos % 36;
    const int yy  = rem / 6;
    const int xx  = rem % 6;

    #pragma unroll
    for (int j = 0; j < 6; ++j) {
        const int e    = j * 256 + tid;
        const int cell = e >> 9;
        const int off  = e & 511;
        pose_s[e] =
            xg[(size_t)((((bb * 14) + (2 * yy + ch)) * 14 + (2 * xx + cell)) * 32) * 16 + off];
    }
    if (tid < CCHUNK) {
        const int cell = tid >> 5, bi = tid & 31;
        a_s[tid] = ag[(size_t)(((bb * 14) + (2 * yy + ch)) * 14 + (2 * xx + cell)) * 32 + bi];
    }
    __syncthreads();

    const int c    = tid & 31;
    const int s    = tid >> 5;
    const int lane = tid & 63;
    const int wv   = tid >> 6;
    const int fc2  = tid >> 3;
    const int fh   = tid & 7;
    const float4* wp = (const float4*)wg;

    for (int it = 0; it < 3; ++it) {
        const float* pin  = (it == 2) ? buf1 : buf0;
        float*       pout = (it == 1) ? buf1 : buf0;

        float4 mu0, mu1, mu2, mu3, is0, is1, is2, is3;
        float Kc = 0.f;
        if (it > 0) {
            const float* q0 = pin + (size_t)pos * (CNCH * PSTRIDE) + fc2 * 33;
            float ms0 = 0.f, ms1 = 0.f, vs0 = 0.f, vs1 = 0.f, rsc = 0.f;
            #pragma unroll
            for (int cc = 0; cc < CNCH; ++cc) {
                const float* q = q0 + cc * PSTRIDE;
                ms0 += q[fh];
                ms1 += q[fh + 8];
                vs0 += q[16 + fh];
                vs1 += q[16 + fh + 8];
                rsc += q[32];
            }
            const float inv   = 1.f / (rsc + 1e-6f);
            const float S     = rsc * inv;
            const float mmu0  = ms0 * inv;
            const float mmu1  = ms1 * inv;
            const float sg0   = vs0 * inv - mmu0 * mmu0 * (2.f - S) + 1e-6f;
            const float sg1   = vs1 * inv - mmu1 * mmu1 * (2.f - S) + 1e-6f;
            float lgs = __logf(sg0) + __logf(sg1);
            #pragma unroll
            for (int msk = 4; msk >= 1; msk >>= 1) lgs += __shfl_xor(lgs, msk);
            const float cost = rsc * (16.f * bu[fc2] + 0.5f * lgs);
            const float ao   = 1.f / (1.f + __expf(-0.001f * (ba[fc2] - cost)));
            mu_tab[fc2 * 16 + fh]      = mmu0;
            mu_tab[fc2 * 16 + fh + 8]  = mmu1;
            i2s_tab[fc2 * 16 + fh]     = 0.5f / sg0;
            i2s_tab[fc2 * 16 + fh + 8] = 0.5f / sg1;
            if (fh == 0) Kc_tab[fc2] = 0.5f * lgs - __logf(ao);
            __syncthreads();
            mu0 = *(const float4*)&mu_tab[c * 16 + 0];
            mu1 = *(const float4*)&mu_tab[c * 16 + 4];
            mu2 = *(const float4*)&mu_tab[c * 16 + 8];
            mu3 = *(const float4*)&mu_tab[c * 16 + 12];
            is0 = *(const float4*)&i2s_tab[c * 16 + 0];
            is1 = *(const float4*)&i2s_tab[c * 16 + 4];
            is2 = *(const float4*)&i2s_tab[c * 16 + 8];
            is3 = *(const float4*)&i2s_tab[c * 16 + 12];
            Kc  = Kc_tab[c];
        }

        float4 ma0, ma1, ma2, ma3, va0, va1, va2, va3;
        ma0 = ma1 = ma2 = ma3 = make_float4(0.f, 0.f, 0.f, 0.f);
        va0 = va1 = va2 = va3 = make_float4(0.f, 0.f, 0.f, 0.f);
        float rs = 0.f;

        const int n0 = ch * CCHUNK + s * 12;
        const float4* wptr = wp + (size_t)(n0 * 32 + c) * 4;
        float4 wa0 = wptr[0], wa1 = wptr[1], wa2 = wptr[2], wa3 = wptr[3];

        #define EM_STEP_COOP(NL)                                               \
        {                                                                      \
            const float4* pp = (const float4*)&pose_s[(NL) << 4];              \
            float4 pa0 = pp[0], pa1 = pp[1], pa2 = pp[2], pa3 = pp[3];         \
            float4 v0, v1, v2, v3;                                             \
            VROWS()                                                            \
            float r;                                                           \
            if (it == 0) {                                                     \
                r = a_s[NL] * 0.03125f;                                        \
            } else {                                                           \
                float t0 = 0.f, t1 = 0.f, t2 = 0.f, t3 = 0.f;                  \
                TACC(t0, v0, mu0, is0)                                         \
                TACC(t1, v1, mu1, is1)                                         \
                TACC(t2, v2, mu2, is2)                                         \
                TACC(t3, v3, mu3, is3)                                         \
                const float lnap = -((t0 + t1) + (t2 + t3)) - Kc;              \
                const float m    = red32_max(lnap);                            \
                const float e    = __expf(lnap - m);                           \
                const float sum  = red32_sum(e);                               \
                r = e / sum;                                                   \
            }                                                                  \
            rs += r;                                                           \
            MACC(ma0, va0, v0)                                                 \
            MACC(ma1, va1, v1)                                                 \
            MACC(ma2, va2, v2)                                                 \
            MACC(ma3, va3, v3)                                                 \
        }

        for (int k = 0; k < 11; ++k) {
            const float4* wnext = wptr + 128;
            float4 wn0 = wnext[0], wn1 = wnext[1], wn2 = wnext[2], wn3 = wnext[3];
            EM_STEP_COOP(s * 12 + k)
            wa0 = wn0; wa1 = wn1; wa2 = wn2; wa3 = wn3; wptr = wnext;
        }
        EM_STEP_COOP(s * 12 + 11)
        #undef EM_STEP_COOP

        XRED(ma0) XRED(ma1) XRED(ma2) XRED(ma3)
        XRED(va0) XRED(va1) XRED(va2) XRED(va3)
        rs += __shfl_xor(rs, 32);
        if (lane < 32) {
            const int base = (wv * 32 + lane) * 33;
            scratch[base+0]=ma0.x;  scratch[base+1]=ma0.y;  scratch[base+2]=ma0.z;  scratch[base+3]=ma0.w;
            scratch[base+4]=ma1.x;  scratch[base+5]=ma1.y;  scratch[base+6]=ma1.z;  scratch[base+7]=ma1.w;
            scratch[base+8]=ma2.x;  scratch[base+9]=ma2.y;  scratch[base+10]=ma2.z; scratch[base+11]=ma2.w;
            scratch[base+12]=ma3.x; scratch[base+13]=ma3.y; scratch[base+14]=ma3.z; scratch[base+15]=ma3.w;
            scratch[base+16]=va0.x; scratch[base+17]=va0.y; scratch[base+18]=va0.z; scratch[base+19]=va0.w;
            scratch[base+20]=va1.x; scratch[base+21]=va1.y; scratch[base+22]=va1.z; scratch[base+23]=va1.w;
            scratch[base+24]=va2.x; scratch[base+25]=va2.y; scratch[base+26]=va2.z; scratch[base+27]=va2.w;
            scratch[base+28]=va3.x; scratch[base+29]=va3.y; scratch[base+30]=va3.z; scratch[base+31]=va3.w;
            rsum_part[wv * 32 + lane] = rs;
        }
        __syncthreads();

        float ms0 = 0.f, ms1 = 0.f, vs0 = 0.f, vs1 = 0.f, rsc = 0.f;
        #pragma unroll
        for (int w = 0; w < 4; ++w) {
            const int base = (w * 32 + fc2) * 33;
            ms0 += scratch[base + fh];
            ms1 += scratch[base + fh + 8];
            vs0 += scratch[base + 16 + fh];
            vs1 += scratch[base + 16 + fh + 8];
            rsc += rsum_part[w * 32 + fc2];
        }
        float* po = pout + (size_t)(pos * CNCH + ch) * PSTRIDE + fc2 * 33;
        po[fh]          = ms0;
        po[fh + 8]      = ms1;
        po[16 + fh]     = vs0;
        po[16 + fh + 8] = vs1;
        if (fh == 0) po[32] = rsc;

        __threadfence();
        grid.sync();
    }

    if (ch == 0) {
        const float* q0p = buf0 + (size_t)pos * (CNCH * PSTRIDE);
        #pragma unroll
        for (int half = 0; half < 2; ++half) {
            const int fc = (tid >> 4) + half * 16;
            const int fp = tid & 15;
            const float* q0 = q0p + fc * 33;
            float ms = 0.f, vs = 0.f, rsc = 0.f;
            #pragma unroll
            for (int cc = 0; cc < CNCH; ++cc) {
                const float* q = q0 + cc * PSTRIDE;
                ms  += q[fp];
                vs  += q[16 + fp];
                rsc += q[32];
            }
            const float inv = 1.f / (rsc + 1e-6f);
            const float S   = rsc * inv;
            const float mu  = ms * inv;
            const float sig = vs * inv - mu * mu * (2.f - S) + 1e-6f;
            float lgs = __logf(sig);
            #pragma unroll
            for (int msk = 8; msk >= 1; msk >>= 1) lgs += __shfl_xor(lgs, msk);
            const float cost = rsc * (16.f * bu[fc] + 0.5f * lgs);
            const float ao   = 1.f / (1.f + __expf(-0.001f * (ba[fc] - cost)));
            outp[(size_t)pos * 512 + fc * 16 + fp] = mu;
            if (fp == 0) outp[147456 + (size_t)pos * 32 + fc] = ao;
        }
    }
}

// ---------------------------------------------------------------------------
// Fallback pipeline: 3 accumulate kernels + finalize (same inner-loop opts).
// ---------------------------------------------------------------------------
template<int IT>
__global__ __launch_bounds__(256) void caps_acc(
    const float* __restrict__ xg,
    const float* __restrict__ ag,
    const float* __restrict__ wg,
    const float* __restrict__ bu,
    const float* __restrict__ ba,
    const float* __restrict__ pin,
    float* __restrict__ pout)
{
    __shared__ __align__(16) float pose_s[CHUNK * 16];
    __shared__ float a_s[CHUNK];
    __shared__ __align__(16) float scratch[4 * 32 * 33];
    __shared__ float rsum_part[4 * 32];
    __shared__ float mu_tab[512];
    __shared__ float i2s_tab[512];
    __shared__ float Kc_tab[32];

    const int tid = threadIdx.x;
    const int blk = blockIdx.x;
    const int pos = blk / NCH;
    const int ch  = blk - pos * NCH;
    const int bb  = pos / 36;
    const int rem = pos % 36;
    const int yy  = rem / 6;
    const int xx  = rem % 6;

    #pragma unroll
    for (int j = 0; j < 3; ++j) {
        const int e    = ch * 768 + j * 256 + tid;
        const int cell = e >> 9;
        const int off  = e & 511;
        const int kh = cell / 3, kw = cell % 3;
        pose_s[j * 256 + tid] =
            xg[(size_t)((((bb * 14) + (2 * yy + kh)) * 14 + (2 * xx + kw)) * 32) * 16 + off];
    }
    if (IT == 0) {
        if (tid < CHUNK) {
            const int e    = ch * CHUNK + tid;
            const int cell = e >> 5;
            const int bi   = e & 31;
            const int kh = cell / 3, kw = cell % 3;
            a_s[tid] = ag[(size_t)(((bb * 14) + (2 * yy + kh)) * 14 + (2 * xx + kw)) * 32 + bi];
        }
    }

    const int fc2 = tid >> 3;
    const int fh  = tid & 7;
    if (IT > 0) {
        const float* q0 = pin + (size_t)pos * (NCH * PSTRIDE) + fc2 * 33;
        float ms0 = 0.f, ms1 = 0.f, vs0 = 0.f, vs1 = 0.f, rsc = 0.f;
        #pragma unroll
        for (int cc = 0; cc < NCH; ++cc) {
            const float* q = q0 + cc * PSTRIDE;
            ms0 += q[fh];
            ms1 += q[fh + 8];
            vs0 += q[16 + fh];
            vs1 += q[16 + fh + 8];
            rsc += q[32];
        }
        const float inv  = 1.f / (rsc + 1e-6f);
        const float S    = rsc * inv;
        const float mmu0 = ms0 * inv;
        const float mmu1 = ms1 * inv;
        const float sg0  = vs0 * inv - mmu0 * mmu0 * (2.f - S) + 1e-6f;
        const float sg1  = vs1 * inv - mmu1 * mmu1 * (2.f - S) + 1e-6f;
        float lgs = __logf(sg0) + __logf(sg1);
        #pragma unroll
        for (int msk = 4; msk >= 1; msk >>= 1) lgs += __shfl_xor(lgs, msk);
        const float cost = rsc * (16.f * bu[fc2] + 0.5f * lgs);
        const float ao   = 1.f / (1.f + __expf(-0.001f * (ba[fc2] - cost)));
        mu_tab[fc2 * 16 + fh]      = mmu0;
        mu_tab[fc2 * 16 + fh + 8]  = mmu1;
        i2s_tab[fc2 * 16 + fh]     = 0.5f / sg0;
        i2s_tab[fc2 * 16 + fh + 8] = 0.5f / sg1;
        if (fh == 0) Kc_tab[fc2] = 0.5f * lgs - __logf(ao);
    }
    __syncthreads();

    const int c    = tid & 31;
    const int s    = tid >> 5;
    const int lane = tid & 63;
    const int wv   = tid >> 6;
    const float4* wp = (const float4*)wg;

    float4 mu0, mu1, mu2, mu3, is0, is1, is2, is3;
    float Kc = 0.f;
    if (IT > 0) {
        mu0 = *(const float4*)&mu_tab[c * 16 + 0];
        mu1 = *(const float4*)&mu_tab[c * 16 + 4];
        mu2 = *(const float4*)&mu_tab[c * 16 + 8];
        mu3 = *(const float4*)&mu_tab[c * 16 + 12];
        is0 = *(const float4*)&i2s_tab[c * 16 + 0];
        is1 = *(const float4*)&i2s_tab[c * 16 + 4];
        is2 = *(const float4*)&i2s_tab[c * 16 + 8];
        is3 = *(const float4*)&i2s_tab[c * 16 + 12];
        Kc  = Kc_tab[c];
    }

    float4 ma0, ma1, ma2, ma3, va0, va1, va2, va3;
    ma0 = ma1 = ma2 = ma3 = make_float4(0.f, 0.f, 0.f, 0.f);
    va0 = va1 = va2 = va3 = make_float4(0.f, 0.f, 0.f, 0.f);
    float rs = 0.f;

    const int n0 = ch * CHUNK + s * 6;
    const float4* wptr = wp + (size_t)(n0 * 32 + c) * 4;
    float4 wa0 = wptr[0], wa1 = wptr[1], wa2 = wptr[2], wa3 = wptr[3];

    #define EM_STEP_ACC(NL)                                                \
    {                                                                      \
        const float4* pp = (const float4*)&pose_s[(NL) << 4];              \
        float4 pa0 = pp[0], pa1 = pp[1], pa2 = pp[2], pa3 = pp[3];         \
        float4 v0, v1, v2, v3;                                             \
        VROWS()                                                            \
        float r;                                                           \
        if (IT == 0) {                                                     \
            r = a_s[NL] * 0.03125f;                                        \
        } else {                                                           \
            float t0 = 0.f, t1 = 0.f, t2 = 0.f, t3 = 0.f;                  \
            TACC(t0, v0, mu0, is0)                                         \
            TACC(t1, v1, mu1, is1)                                         \
            TACC(t2, v2, mu2, is2)                                         \
            TACC(t3, v3, mu3, is3)                                         \
            const float lnap = -((t0 + t1) + (t2 + t3)) - Kc;              \
            const float m    = red32_max(lnap);                            \
            const float e    = __expf(lnap - m);                           \
            const float sum  = red32_sum(e);                               \
            r = e / sum;                                                   \
        }                                                                  \
        rs += r;                                                           \
        MACC(ma0, va0, v0)                                                 \
        MACC(ma1, va1, v1)                                                 \
        MACC(ma2, va2, v2)                                                 \
        MACC(ma3, va3, v3)                                                 \
    }

    for (int k = 0; k < 5; ++k) {
        const float4* wnext = wptr + 128;
        float4 wn0 = wnext[0], wn1 = wnext[1], wn2 = wnext[2], wn3 = wnext[3];
        EM_STEP_ACC(s * 6 + k)
        wa0 = wn0; wa1 = wn1; wa2 = wn2; wa3 = wn3; wptr = wnext;
    }
    EM_STEP_ACC(s * 6 + 5)
    #undef EM_STEP_ACC

    XRED(ma0) XRED(ma1) XRED(ma2) XRED(ma3)
    XRED(va0) XRED(va1) XRED(va2) XRED(va3)
    rs += __shfl_xor(rs, 32);
    if (lane < 32) {
        const int base = (wv * 32 + lane) * 33;
        scratch[base+0]=ma0.x;  scratch[base+1]=ma0.y;  scratch[base+2]=ma0.z;  scratch[base+3]=ma0.w;
        scratch[base+4]=ma1.x;  scratch[base+5]=ma1.y;  scratch[base+6]=ma1.z;  scratch[base+7]=ma1.w;
        scratch[base+8]=ma2.x;  scratch[base+9]=ma2.y;  scratch[base+10]=ma2.z; scratch[base+11]=ma2.w;
        scratch[base+12]=ma3.x; scratch[base+13]=ma3.y; scratch[base+14]=ma3.z; scratch[base+15]=ma3.w;
        scratch[base+16]=va0.x; scratch[base+17]=va0.y; scratch[base+18]=va0.z; scratch[base+19]=va0.w;
        scratch[base+20]=va1.x; scratch[base+21]=va1.y; scratch[base+22]=va1.z; scratch[base+23]=va1.w;
        scratch[base+24]=va2.x; scratch[base+25]=va2.y; scratch[base+26]=va2.z; scratch[base+27]=va2.w;
        scratch[base+28]=va3.x; scratch[base+29]=va3.y; scratch[base+30]=va3.z; scratch[base+31]=va3.w;
        rsum_part[wv * 32 + lane] = rs;
    }
    __syncthreads();

    float ms0 = 0.f, ms1 = 0.f, vs0 = 0.f, vs1 = 0.f, rsc = 0.f;
    #pragma unroll
    for (int w = 0; w < 4; ++w) {
        const int base = (w * 32 + fc2) * 33;
        ms0 += scratch[base + fh];
        ms1 += scratch[base + fh + 8];
        vs0 += scratch[base + 16 + fh];
        vs1 += scratch[base + 16 + fh + 8];
        rsc += rsum_part[w * 32 + fc2];
    }
    float* po = pout + (size_t)(pos * NCH + ch) * PSTRIDE + fc2 * 33;
    po[fh]          = ms0;
    po[fh + 8]      = ms1;
    po[16 + fh]     = vs0;
    po[16 + fh + 8] = vs1;
    if (fh == 0) po[32] = rsc;
}

__global__ __launch_bounds__(512) void caps_fin(
    const float* __restrict__ pin,
    const float* __restrict__ bu,
    const float* __restrict__ ba,
    float* __restrict__ outp)
{
    const int tid = threadIdx.x;
    const int pos = blockIdx.x;
    const int fc = tid >> 4, fp = tid & 15;
    const float* q0 = pin + (size_t)pos * (NCH * PSTRIDE) + fc * 33;
    float ms = 0.f, vs = 0.f, rsc = 0.f;
    #pragma unroll
    for (int cc = 0; cc < NCH; ++cc) {
        const float* q = q0 + cc * PSTRIDE;
        ms  += q[fp];
        vs  += q[16 + fp];
        rsc += q[32];
    }
    const float inv = 1.f / (rsc + 1e-6f);
    const float S   = rsc * inv;
    const float mu  = ms * inv;
    const float sig = vs * inv - mu * mu * (2.f - S) + 1e-6f;
    float lgs = __logf(sig);
    #pragma unroll
    for (int msk = 8; msk >= 1; msk >>= 1) lgs += __shfl_xor(lgs, msk);
    const float cost = rsc * (16.f * bu[fc] + 0.5f * lgs);
    const float ao   = 1.f / (1.f + __expf(-0.001f * (ba[fc] - cost)));
    outp[(size_t)pos * 512 + tid] = mu;
    if (fp == 0) outp[147456 + (size_t)pos * 32 + fc] = ao;
}

// ---------------------------------------------------------------------------
// Fallback: single fused kernel (used only if workspace too small).
// ---------------------------------------------------------------------------
__global__ __launch_bounds__(512) void convcaps_kernel(
    const float* __restrict__ xg,
    const float* __restrict__ ag,
    const float* __restrict__ wg,
    const float* __restrict__ bu,
    const float* __restrict__ ba,
    float* __restrict__ outp)
{
    __shared__ __align__(16) float pose_s[4608];
    __shared__ float a_s[288];
    __shared__ __align__(16) float scratch[8448];
    __shared__ float rsum_part[256];
    __shared__ float mu_tab[512];
    __shared__ float i2s_tab[512];
    __shared__ float Kc_tab[32];

    const int tid = threadIdx.x;
    const int pos = blockIdx.x;
    const int bb  = pos / 36;
    const int rem = pos % 36;
    const int yy  = rem / 6;
    const int xx  = rem % 6;

    #pragma unroll
    for (int wi = 0; wi < 9; ++wi) {
        const int kh = wi / 3, kw = wi % 3;
        const float* src =
            xg + (size_t)((((bb * 14) + (2 * yy + kh)) * 14 + (2 * xx + kw)) * 32) * 16;
        pose_s[wi * 512 + tid] = src[tid];
    }
    if (tid < 288) {
        const int wi = tid >> 5, bi = tid & 31;
        const int kh = wi / 3, kw = wi % 3;
        a_s[tid] = ag[(size_t)(((bb * 14) + (2 * yy + kh)) * 14 + (2 * xx + kw)) * 32 + bi];
    }
    __syncthreads();

    const int c    = tid & 31;
    const int s    = tid >> 5;
    const int lane = tid & 63;
    const int wv   = tid >> 6;
    const float4* wp = (const float4*)wg;

    for (int it = 0; it < 3; ++it) {
        float mu_c[16], i2s_c[16], Kc = 0.f;
        if (it > 0) {
            #pragma unroll
            for (int p = 0; p < 16; ++p) {
                mu_c[p]  = mu_tab[c * 16 + p];
                i2s_c[p] = i2s_tab[c * 16 + p];
            }
            Kc = Kc_tab[c];
        }
        float macc[16], vacc[16], rs = 0.f;
        #pragma unroll
        for (int p = 0; p < 16; ++p) { macc[p] = 0.f; vacc[p] = 0.f; }

        for (int k = 0; k < 18; ++k) {
            const int n = s * 18 + k;
            const float4* pp = (const float4*)&pose_s[n << 4];
            float pf[16];
            float4 q;
            q = pp[0]; pf[0]=q.x; pf[1]=q.y; pf[2]=q.z;  pf[3]=q.w;
            q = pp[1]; pf[4]=q.x; pf[5]=q.y; pf[6]=q.z;  pf[7]=q.w;
            q = pp[2]; pf[8]=q.x; pf[9]=q.y; pf[10]=q.z; pf[11]=q.w;
            q = pp[3]; pf[12]=q.x; pf[13]=q.y; pf[14]=q.z; pf[15]=q.w;
            const int wbase = (n * 32 + c) * 4;
            float v[16];
            #pragma unroll
            for (int p = 0; p < 16; ++p) v[p] = 0.f;
            #pragma unroll
            for (int j = 0; j < 4; ++j) {
                const float4 w = wp[wbase + j];
                #pragma unroll
                for (int i = 0; i < 4; ++i) {
                    const float pj = pf[i * 4 + j];
                    v[i*4+0] = fmaf(pj, w.x, v[i*4+0]);
                    v[i*4+1] = fmaf(pj, w.y, v[i*4+1]);
                    v[i*4+2] = fmaf(pj, w.z, v[i*4+2]);
                    v[i*4+3] = fmaf(pj, w.w, v[i*4+3]);
                }
            }
            float r;
            if (it == 0) {
                r = a_s[n] * 0.03125f;
            } else {
                float t = 0.f;
                #pragma unroll
                for (int p = 0; p < 16; ++p) {
                    float d = v[p] - mu_c[p];
                    t = fmaf(d * d, i2s_c[p], t);
                }
                float lnap = -t - Kc;
                float m = lnap;
                #pragma unroll
                for (int msk = 16; msk >= 1; msk >>= 1) m = fmaxf(m, __shfl_xor(m, msk));
                float e = __expf(lnap - m);
                float sum = e;
                #pragma unroll
                for (int msk = 16; msk >= 1; msk >>= 1) sum += __shfl_xor(sum, msk);
                r = e / sum;
            }
            rs += r;
            #pragma unroll
            for (int p = 0; p < 16; ++p) {
                float rv = r * v[p];
                macc[p] += rv;
                vacc[p] = fmaf(rv, v[p], vacc[p]);
            }
        }

        #pragma unroll
        for (int p = 0; p < 16; ++p) {
            macc[p] += __shfl_xor(macc[p], 32);
            vacc[p] += __shfl_xor(vacc[p], 32);
        }
        rs += __shfl_xor(rs, 32);
        if (lane < 32) {
            const int base = (wv * 32 + lane) * 33;
            #pragma unroll
            for (int p = 0; p < 16; ++p) {
                scratch[base + p]      = macc[p];
                scratch[base + 16 + p] = vacc[p];
            }
            rsum_part[wv * 32 + lane] = rs;
        }
        __syncthreads();

        const int fc = tid >> 4, fp = tid & 15;
        float ms = 0.f, vs = 0.f, rsc = 0.f;
        #pragma unroll
        for (int w = 0; w < 8; ++w) {
            ms  += scratch[(w * 32 + fc) * 33 + fp];
            vs  += scratch[(w * 32 + fc) * 33 + 16 + fp];
            rsc += rsum_part[w * 32 + fc];
        }
        const float inv = 1.f / (rsc + 1e-6f);
        const float S   = rsc * inv;
        const float mu  = ms * inv;
        const float sig = vs * inv - mu * mu * (2.f - S) + 1e-6f;
        float lgs = __logf(sig);
        #pragma unroll
        for (int msk = 8; msk >= 1; msk >>= 1) lgs += __shfl_xor(lgs, msk);
        const float cost = rsc * (16.f * bu[fc] + 0.5f * lgs);
        const float ao   = 1.f / (1.f + __expf(-0.001f * (ba[fc] - cost)));

        mu_tab[fc * 16 + fp]  = mu;
        i2s_tab[fc * 16 + fp] = 0.5f / sig;
        if (fp == 0) Kc_tab[fc] = 0.5f * lgs - __logf(ao);

        if (it == 2) {
            outp[(size_t)pos * 512 + tid] = mu;
            if (fp == 0) outp[147456 + (size_t)pos * 32 + fc] = ao;
        }
        __syncthreads();
    }
}

extern "C" void kernel_launch(void* const* d_in, const int* in_sizes, int n_in,
                              void* d_out, int out_size, void* d_ws, size_t ws_size,
                              hipStream_t stream) {
    (void)in_sizes; (void)n_in; (void)out_size;
    const float* x  = (const float*)d_in[0];
    const float* a  = (const float*)d_in[1];
    const float* w  = (const float*)d_in[2];
    const float* bu = (const float*)d_in[3];
    const float* ba = (const float*)d_in[4];
    float* out = (float*)d_out;

    const size_t buf_elems = (size_t)NPOS * NCH * PSTRIDE;
    if (ws_size < 2 * buf_elems * sizeof(float)) {
        convcaps_kernel<<<dim3(288), dim3(512), 0, stream>>>(x, a, w, bu, ba, out);
        return;
    }
    float* buf0 = (float*)d_ws;
    float* buf1 = buf0 + buf_elems;

    static int coop_ok = -1;
    if (coop_ok < 0) {
        int dev = 0;
        (void)hipGetDevice(&dev);
        int coopAttr = 0, nCU = 0, nb = 0;
        (void)hipDeviceGetAttribute(&coopAttr, hipDeviceAttributeCooperativeLaunch, dev);
        (void)hipDeviceGetAttribute(&nCU, hipDeviceAttributeMultiprocessorCount, dev);
        hipError_t oe = hipOccupancyMaxActiveBlocksPerMultiprocessor(&nb, caps_coop, 256, 0);
        coop_ok = (coopAttr != 0 && oe == hipSuccess && nCU > 0 &&
                   (long)nb * (long)nCU >= (long)(NPOS * CNCH)) ? 1 : 0;
    }

    if (coop_ok == 1) {
        void* args[8];
        args[0] = (void*)&x;  args[1] = (void*)&a;  args[2] = (void*)&w;
        args[3] = (void*)&bu; args[4] = (void*)&ba;
        args[5] = (void*)&buf0; args[6] = (void*)&buf1; args[7] = (void*)&out;
        hipError_t e = hipLaunchCooperativeKernel((const void*)caps_coop,
                                                  dim3(NPOS * CNCH), dim3(256),
                                                  args, 0, stream);
        if (e == hipSuccess) return;
        coop_ok = 0;
    }

    caps_acc<0><<<dim3(NPOS * NCH), dim3(256), 0, stream>>>(x, a, w, bu, ba, nullptr, buf0);
    caps_acc<1><<<dim3(NPOS * NCH), dim3(256), 0, stream>>>(x, a, w, bu, ba, buf0, buf1);
    caps_acc<2><<<dim3(NPOS * NCH), dim3(256), 0, stream>>>(x, a, w, bu, ba, buf1, buf0);
    caps_fin<<<dim3(NPOS), dim3(512), 0, stream>>>(buf0, bu, ba, out);
}